// Round 4
// baseline (52.030 us; speedup 1.0000x reference)
//
#include <hip/hip_runtime.h>
#include <hip/hip_bf16.h>

// RoPE: out[b,s,2j]   = cos[pos,j]*x[b,s,2j] - sin[pos,j]*x[b,s,2j+1]
//       out[b,s,2j+1] = sin[pos,j]*x[b,s,2j] + cos[pos,j]*x[b,s,2j+1]
// D_K = 128 -> 64 pairs -> 32 float4 per row.
//
// R3: UNROLL 4 -> 8 (more load chains in flight), 32-bit indexing
// (total buffer 134 MB < 2^31 B so int offsets are safe and cheaper).

#define DK 128
#define UNROLL 8

typedef float f32x4 __attribute__((ext_vector_type(4)));
typedef float f32x2 __attribute__((ext_vector_type(2)));

__global__ __launch_bounds__(256)
void rope_f32_kernel(const float* __restrict__ x,
                     const int* __restrict__ pos,
                     const float* __restrict__ sin_tab,
                     const float* __restrict__ cos_tab,
                     float* __restrict__ out) {
    const int base = blockIdx.x * (256 * UNROLL) + threadIdx.x;
    const f32x4* __restrict__ xv4 = reinterpret_cast<const f32x4*>(x);
    f32x4* __restrict__ ov4 = reinterpret_cast<f32x4*>(out);

    int   idx[UNROLL];
    int   p[UNROLL];
    f32x4 xv[UNROLL];
    f32x2 s[UNROLL], c[UNROLL];

    // 1) issue all pos loads (independent)
    #pragma unroll
    for (int k = 0; k < UNROLL; ++k) {
        idx[k] = base + k * 256;
        p[k] = pos[idx[k] >> 5];           // row = idx / 32
    }
    // 2) issue all x loads (independent of pos)
    #pragma unroll
    for (int k = 0; k < UNROLL; ++k) {
        xv[k] = __builtin_nontemporal_load(&xv4[idx[k]]);
    }
    // 3) table loads (dependent on pos, 8 chains in flight)
    #pragma unroll
    for (int k = 0; k < UNROLL; ++k) {
        const int f4    = idx[k] & 31;
        const int tbase = p[k] * (DK / 2) + f4 * 2;   // max ~524k, int-safe
        s[k] = *reinterpret_cast<const f32x2*>(&sin_tab[tbase]);
        c[k] = *reinterpret_cast<const f32x2*>(&cos_tab[tbase]);
    }
    // 4) compute + store
    #pragma unroll
    for (int k = 0; k < UNROLL; ++k) {
        f32x4 o;
        o.x = c[k].x * xv[k].x - s[k].x * xv[k].y;
        o.y = s[k].x * xv[k].x + c[k].x * xv[k].y;
        o.z = c[k].y * xv[k].z - s[k].y * xv[k].w;
        o.w = s[k].y * xv[k].z + c[k].y * xv[k].w;
        __builtin_nontemporal_store(o, &ov4[idx[k]]);
    }
}

extern "C" void kernel_launch(void* const* d_in, const int* in_sizes, int n_in,
                              void* d_out, int out_size, void* d_ws, size_t ws_size,
                              hipStream_t stream) {
    const float* x       = (const float*)d_in[0];
    const int*   posp    = (const int*)d_in[1];
    const float* sin_tab = (const float*)d_in[2];
    const float* cos_tab = (const float*)d_in[3];
    float*       out     = (float*)d_out;

    const int n4 = out_size / 4;                     // 8388608 float4s
    const int per_block = 256 * UNROLL;              // 2048
    const int grid = (n4 + per_block - 1) / per_block;  // exact: 4096

    rope_f32_kernel<<<grid, 256, 0, stream>>>(x, posp, sin_tab, cos_tab, out);
}